// Round 2
// baseline (1009.606 us; speedup 1.0000x reference)
//
#include <hip/hip_runtime.h>

typedef _Float16 h2   __attribute__((ext_vector_type(2)));
typedef _Float16 h4   __attribute__((ext_vector_type(4)));
typedef _Float16 half8 __attribute__((ext_vector_type(8)));
typedef float f32x4   __attribute__((ext_vector_type(4)));
typedef unsigned long long u64;

#define MFMA16(a,b,c) __builtin_amdgcn_mfma_f32_16x16x32_f16((a),(b),(c),0,0,0)
#define ATOMIC_ST64(p,v) __hip_atomic_store((p),(v),__ATOMIC_RELAXED,__HIP_MEMORY_SCOPE_AGENT)
#define ATOMIC_LD64(p)   __hip_atomic_load((p),__ATOMIC_RELAXED,__HIP_MEMORY_SCOPE_AGENT)
// Light barrier: rendezvous + LDS drain only. Global loads/stores stay in flight.
#define BAR_LDS() do { asm volatile("s_waitcnt lgkmcnt(0)" ::: "memory"); \
                       __builtin_amdgcn_s_barrier();                      \
                       asm volatile("" ::: "memory"); } while (0)

// B=512, T=64, STOCH=30, DETER=200, HIDDEN=200, A=12, EMBED=1024
// out row = [stoch_po(30), mean_po(30), std_po(30), stoch_pr(30), mean_pr(30), std_pr(30), deter(200)] = 380

// Fragment regions (1KB blocks = 64 lanes x 8 halves), B-frag order [nt][ks][lane][8]
// INP: NT=13 KS=2 @0(26) | GRU: NT=38 KS=13 @26(494) | IMG: NT=13 KS=7 @520(91)
// OBSD: NT=13 KS=7 @611(91) | IMS: NT=4 KS=7 @702(28) | OBS: NT=4 KS=7 @730(28)
// W2: NT=13 KS=32 @758(416) -> 1174 blocks
#define EP_HALVES ((size_t)32768*200)
#define ZWORDS 118784   // (2*32*1600 + 2*32*256) u64 exchange words zeroed per launch

__global__ void prep_frags(const float* __restrict__ inpW, const float* __restrict__ gruW,
                           const float* __restrict__ imgW, const float* __restrict__ obsoutW,
                           const float* __restrict__ imsW, const float* __restrict__ obsW,
                           _Float16* __restrict__ frags) {
    int gb = blockIdx.x, lane = threadIdx.x;
    const float* src; int KS, K, N, ld, roff = 0, local;
    if (gb < 26)       { src = inpW;    KS = 2;  K = 42;   N = 200; ld = 200; local = gb; }
    else if (gb < 520) { src = gruW;    KS = 13; K = 400;  N = 600; ld = 600; local = gb - 26; }
    else if (gb < 611) { src = imgW;    KS = 7;  K = 200;  N = 200; ld = 200; local = gb - 520; }
    else if (gb < 702) { src = obsoutW; KS = 7;  K = 200;  N = 200; ld = 200; local = gb - 611; }
    else if (gb < 730) { src = imsW;    KS = 7;  K = 200;  N = 60;  ld = 60;  local = gb - 702; }
    else if (gb < 758) { src = obsW;    KS = 7;  K = 200;  N = 60;  ld = 60;  local = gb - 730; }
    else               { src = obsoutW; KS = 32; K = 1024; N = 200; ld = 200; roff = 200; local = gb - 758; }
    int nt = local / KS, ks = local % KS;
    int n  = nt * 16 + (lane & 15);
    int k0 = ks * 32 + (lane >> 4) * 8;
    half8 v;
#pragma unroll
    for (int j = 0; j < 8; ++j) {
        int k = k0 + j;
        float f = (k < K && n < N) ? src[(size_t)(k + roff) * ld + n] : 0.0f;
        v[j] = (_Float16)f;
    }
    *(half8*)(frags + (size_t)gb * 512 + lane * 8) = v;
}

// ep[row][0..199] = embed[row] @ obs_out_W[200:,:]  (f16), row = b*64+t
// also zeroes the tagged-exchange buffers (fresh tags every launch/graph-replay)
__global__ __launch_bounds__(256) void ep_gemm(const float* __restrict__ embed,
                                               const _Float16* __restrict__ w2f,
                                               _Float16* __restrict__ ep,
                                               u64* __restrict__ zmem) {
    {
        int gid = blockIdx.x * 256 + threadIdx.x;
        if (gid < ZWORDS) zmem[gid] = 0ull;
    }
    __shared__ __align__(16) _Float16 aE[16 * 1048];
    int tid = threadIdx.x;
    int rb = blockIdx.x * 16;
#pragma unroll
    for (int i = 0; i < 16; ++i) {
        float4 e = *((const float4*)(embed + (size_t)(rb + i) * 1024) + tid);
        h4 hv; hv[0] = (_Float16)e.x; hv[1] = (_Float16)e.y; hv[2] = (_Float16)e.z; hv[3] = (_Float16)e.w;
        *(h4*)(aE + i * 1048 + tid * 4) = hv;
    }
    __syncthreads();
    int w = tid >> 6, lane = tid & 63, m = lane & 15, q = lane >> 4;
    f32x4 acc[4] = {};
    int nts[4]; int ntc = 0;
    for (int nt = w; nt < 13; nt += 4) nts[ntc++] = nt;
    half8 bb[2][4];
#pragma unroll
    for (int j = 0; j < 4; ++j) if (j < ntc)
        bb[0][j] = *(const half8*)(w2f + ((size_t)(nts[j] * 32) * 64 + lane) * 8);
#pragma unroll
    for (int ks = 0; ks < 32; ++ks) {
        int cur = ks & 1, nxt = cur ^ 1;
        if (ks < 31) {
#pragma unroll
            for (int j = 0; j < 4; ++j) if (j < ntc)
                bb[nxt][j] = *(const half8*)(w2f + ((size_t)(nts[j] * 32 + ks + 1) * 64 + lane) * 8);
        }
        half8 a = *(const half8*)(aE + m * 1048 + ks * 32 + q * 8);
#pragma unroll
        for (int j = 0; j < 4; ++j) if (j < ntc)
            acc[j] = MFMA16(a, bb[cur][j], acc[j]);
    }
    for (int j = 0; j < ntc; ++j) {
        int col = nts[j] * 16 + m;
        if (col < 200) {
#pragma unroll
            for (int i = 0; i < 4; ++i)
                ep[(size_t)(rb + q * 4 + i) * 200 + col] = (_Float16)acc[j][i];
        }
    }
}

__device__ __forceinline__ float sigm_(float x) { return 1.0f / (1.0f + __expf(-x)); }
__device__ __forceinline__ float tanh_(float x) { float e = __expf(2.0f * x); return 1.0f - 2.0f / (e + 1.0f); }
__device__ __forceinline__ float elu_(float x)  { return x > 0.0f ? x : __expf(x) - 1.0f; }
__device__ __forceinline__ float sp_(float x)   { return fmaxf(x, 0.0f) + log1pf(__expf(-fabsf(x))); }
__device__ __forceinline__ unsigned packh2(float a, float b) {
    h2 p; p[0] = (_Float16)a; p[1] = (_Float16)b;
    return __builtin_bit_cast(unsigned, p);
}
__device__ __forceinline__ unsigned poll64(const u64* p, unsigned want, u64 v) {
    int it = 0;
    while ((unsigned)(v >> 32) != want) {
        __builtin_amdgcn_s_sleep(1);
        v = ATOMIC_LD64(p);
        if (++it > (1 << 20)) break;
    }
    return (unsigned)v;
}

// Quad design: group g = 16 rows, WGs wg=0..3 (blockIdx = wg*32+g).
//   wg quarter: deter dims n in [50*wg, 50*wg+50)
//   GRU tiles per wg (12): gate0 {3wg..3wg+3}, gate1 {12+3wg..+3}, gate2 {25+3wg..+3}
//     -> gates(n-range) reads ONLY local parts (LDS).
//   Cross-WG exchange is SELF-SYNCHRONIZING: each exchanged h2 value is one relaxed
//   agent-scope u64 {tag=t+1 | data}. Writers fire tagged stores as soon as each
//   value is computed (no drain, no flag); readers poll the exact words they need
//   until the tag matches -> ONE L3 round trip per exchange instead of three
//   (drain+flag+spin+data). Buffers are t-parity double-buffered; overwrite at t+2
//   happens-after all readers of t via the gather->gates->qdet dependency chain
//   (same argument as the old flag protocol). ep_gemm zeroes all tags per launch,
//   so stale tags from a previous launch/graph replay can never match.
//   wg0: P3(IMG)+P4(IMS)+P5 prior outs; wg2: P3(OBSD+ep)+P4(OBS)+P5 post outs + stoch publish;
//   wg1/wg3: only GRU quarter + gates; idle through P3-P5.
__global__ __launch_bounds__(512) __attribute__((amdgpu_waves_per_eu(2, 2))) void rssm_scan(
    const float* __restrict__ action, const float* __restrict__ npr, const float* __restrict__ npo,
    const float* __restrict__ inp_b, const float* __restrict__ gru_b,
    const float* __restrict__ img_b, const float* __restrict__ obsout_b,
    const float* __restrict__ ims_b, const float* __restrict__ obs_b,
    const _Float16* __restrict__ frags, const _Float16* __restrict__ ep,
    u64* __restrict__ qdet, u64* __restrict__ stochb,
    float* __restrict__ out) {

    __shared__ __align__(16) unsigned actI[16 * 36];    // [stoch(15p) action(6p) zeropad]
    __shared__ __align__(16) unsigned actG[16 * 212];   // [x(100p) deter(100p) zeropad]
    __shared__ __align__(16) unsigned actX[16 * 116];   // h (wg0) / ho (wg2)
    __shared__ __align__(16) _Float16 parts[16 * 208];  // local 12 GRU tiles (f16)
    __shared__ float statspre[16 * 65];
    __shared__ float bias[1320];  // inp200 | gru600 | img200 | obsout200 | ims60 | obs60

    const _Float16* Finp  = frags;
    const _Float16* Fgru  = frags + (size_t)26  * 512;
    const _Float16* Fimg  = frags + (size_t)520 * 512;
    const _Float16* Fobsd = frags + (size_t)611 * 512;
    const _Float16* Fims  = frags + (size_t)702 * 512;
    const _Float16* Fobs  = frags + (size_t)730 * 512;

    const int tid = threadIdx.x, w = tid >> 6, lane = tid & 63, m = lane & 15, q = lane >> 4;
    const int g = blockIdx.x & 31, wg = blockIdx.x >> 5;
    const int rb = g * 16;
    const bool post = (wg >= 2);
    const bool statside = (wg == 0) || (wg == 2);
    const int colA = w * 16 + m;          // P3 columns (t-invariant)
    const int colB = (8 + w) * 16 + m;

    for (int i = tid; i < 1320; i += 512) {
        float v;
        if (i < 200) v = inp_b[i];
        else if (i < 800)  v = gru_b[i - 200];
        else if (i < 1000) v = img_b[i - 800];
        else if (i < 1200) v = obsout_b[i - 1000];
        else if (i < 1260) v = ims_b[i - 1200];
        else               v = obs_b[i - 1260];
        bias[i] = v;
    }
    for (int i = tid; i < 16 * 36;  i += 512) actI[i] = 0u;
    for (int i = tid; i < 16 * 212; i += 512) actG[i] = 0u;
    for (int i = tid; i < 16 * 116; i += 512) actX[i] = 0u;

    // ---- persistent register weights ----
    half8 bgru0[13];  // GRU tile A: w<4 -> gate0 tile 3wg+w ; w>=4 -> gate1 tile 12+3wg+(w-4)
    {
        int tA = (w < 4) ? (3 * wg + w) : (12 + 3 * wg + (w - 4));
#pragma unroll
        for (int ks = 0; ks < 13; ++ks)
            bgru0[ks] = *(const half8*)(Fgru + ((size_t)(tA * 13 + ks) * 64 + lane) * 8);
    }
    half8 bgru1[13];  // w<4: gate2 tile 25+3wg+w
    if (w < 4) {
        int tB = 25 + 3 * wg + w;
#pragma unroll
        for (int ks = 0; ks < 13; ++ks)
            bgru1[ks] = *(const half8*)(Fgru + ((size_t)(tB * 13 + ks) * 64 + lane) * 8);
    }
    // P1 INP weights, persistent
    half8 bi0[2], bi1[2];
#pragma unroll
    for (int ks = 0; ks < 2; ++ks)
        bi0[ks] = *(const half8*)(Finp + ((size_t)(w * 2 + ks) * 64 + lane) * 8);
    if (w < 5) {
#pragma unroll
        for (int ks = 0; ks < 2; ++ks)
            bi1[ks] = *(const half8*)(Finp + ((size_t)((8 + w) * 2 + ks) * 64 + lane) * 8);
    }
    const _Float16* F3 = post ? Fobsd : Fimg;
    const _Float16* F4 = post ? Fobs : Fims;
    half8 bp3a[7];    // P3 tile w (0..7)
    if (statside) {
#pragma unroll
        for (int ks = 0; ks < 7; ++ks)
            bp3a[ks] = *(const half8*)(F3 + ((size_t)(w * 7 + ks) * 64 + lane) * 8);
    }
    half8 bp4[7];     // w in 4..7: stats tile w-4
    if (statside && w >= 4) {
#pragma unroll
        for (int ks = 0; ks < 7; ++ks)
            bp4[ks] = *(const half8*)(F4 + ((size_t)((w - 4) * 7 + ks) * 64 + lane) * 8);
    }
    __syncthreads();

    for (int t = 0; t < 64; ++t) {
        // ---- prefetch region: ep (wg2), action, noise — all fire-and-forget ----
        h2 epA[4], epB[4];
        if (post && !(m & 1)) {
#pragma unroll
            for (int i = 0; i < 4; ++i)
                epA[i] = *(const h2*)(ep + ((size_t)(rb + q * 4 + i) * 64 + t) * 200 + colA);
            if (w < 5 && colB < 200) {
#pragma unroll
                for (int i = 0; i < 4; ++i)
                    epB[i] = *(const h2*)(ep + ((size_t)(rb + q * 4 + i) * 64 + t) * 200 + colB);
            }
        }
        float2 a2 = make_float2(0.0f, 0.0f);
        if (tid < 96) {
            int r = tid / 6, cp = tid % 6;
            a2 = *(const float2*)(action + ((size_t)(rb + r) * 64 + t) * 12 + 2 * cp);
        }
        float2 nz = make_float2(0.0f, 0.0f);
        if (statside && tid < 240) {
            int r = tid / 15, cp = tid % 15;
            const float* ns = post ? npo : npr;
            nz = *(const float2*)(ns + ((size_t)(rb + r) * 64 + t) * 30 + 2 * cp);
        }

        // ---- top: stoch poll (wg != 2, t>0): tagged single-RT read ----
        if (t > 0 && wg != 2 && tid < 240) {
            int r = tid / 15, cp = tid % 15;
            const u64* sp = stochb + (size_t)(((t - 1) & 1) * 32 + g) * 256 + r * 16 + cp;
            actI[r * 36 + cp] = poll64(sp, (unsigned)t, ATOMIC_LD64(sp));
        }
        if (tid < 96) {
            int r = tid / 6, cp = tid % 6;
            actI[r * 36 + 15 + cp] = packh2(a2.x, a2.y);
        }
        BAR_LDS();

        // ---- P1: x = elu(cat(stoch,action)@inp_W + b) -> actG[0..99] ----
        {
            f32x4 acc = {}, acc2 = {};
#pragma unroll
            for (int ks = 0; ks < 2; ++ks) {
                half8 a = *(const half8*)(actI + m * 36 + ks * 16 + q * 4);
                acc = MFMA16(a, bi0[ks], acc);
                if (w < 5) acc2 = MFMA16(a, bi1[ks], acc2);
            }
            f32x4 accN;
#pragma unroll
            for (int i = 0; i < 4; ++i) accN[i] = __shfl_xor(acc[i], 1);
            if (!(m & 1)) {
                int col = w * 16 + m;   // <= 127 < 200
#pragma unroll
                for (int i = 0; i < 4; ++i)
                    actG[(q * 4 + i) * 212 + (col >> 1)] =
                        packh2(elu_(acc[i] + bias[col]), elu_(accN[i] + bias[col + 1]));
            }
            if (w < 5) {
                f32x4 acc2N;
#pragma unroll
                for (int i = 0; i < 4; ++i) acc2N[i] = __shfl_xor(acc2[i], 1);
                if (!(m & 1)) {
                    int col = (8 + w) * 16 + m;
                    if (col < 200) {
#pragma unroll
                        for (int i = 0; i < 4; ++i)
                            actG[(q * 4 + i) * 212 + (col >> 1)] =
                                packh2(elu_(acc2[i] + bias[col]), elu_(acc2N[i] + bias[col + 1]));
                    }
                }
            }
        }
        BAR_LDS();

        // ---- P2: local 12 GRU tiles -> parts (LDS) ----
        {
            f32x4 a0 = {}, a1 = {};
#pragma unroll
            for (int ks = 0; ks < 13; ++ks) {
                half8 a = *(const half8*)(actG + m * 212 + ks * 16 + q * 4);
                a0 = MFMA16(a, bgru0[ks], a0);
                if (w < 4) a1 = MFMA16(a, bgru1[ks], a1);
            }
#pragma unroll
            for (int i = 0; i < 4; ++i)
                parts[(q * 4 + i) * 208 + w * 16 + m] = (_Float16)a0[i];
            if (w < 4) {
#pragma unroll
                for (int i = 0; i < 4; ++i)
                    parts[(q * 4 + i) * 208 + (8 + w) * 16 + m] = (_Float16)a1[i];
            }
        }
        // prefetch P3 tile 8+w (stays in flight across light barriers)
        half8 pf3[7];
        if (statside && w < 5) {
#pragma unroll
            for (int ks = 0; ks < 7; ++ks)
                pf3[ks] = *(const half8*)(F3 + ((size_t)((8 + w) * 7 + ks) * 64 + lane) * 8);
        }
        BAR_LDS();

        // ---- gates: own n-quarter -> deter_new; tagged qdet stores fire immediately ----
        u64* qd = qdet + (size_t)((t & 1) * 32 + g) * 1600;
        if (tid < 400) {
            int r = tid / 25, p = tid % 25;
            int n0 = 50 * wg + 2 * p;
            float pg[3][2];
#pragma unroll
            for (int j = 0; j < 3; ++j) {
                int cg = n0 + 200 * j;
                int bj = (j == 0) ? 3 * wg : (j == 1) ? 12 + 3 * wg : 25 + 3 * wg;
                int lt = 4 * j + (cg >> 4) - bj;
                h2 v = *(const h2*)(parts + r * 208 + lt * 16 + (cg & 15));
                pg[j][0] = (float)v[0] + bias[200 + cg];
                pg[j][1] = (float)v[1] + bias[200 + cg + 1];
            }
            h2 dold = *(const h2*)&actG[r * 212 + 100 + (n0 >> 1)];
            float dn[2];
#pragma unroll
            for (int e = 0; e < 2; ++e) {
                float reset = sigm_(pg[0][e]);
                float cand  = tanh_(reset * pg[1][e]);
                float upd   = sigm_(pg[2][e] - 1.0f);
                dn[e] = upd * cand + (1.0f - upd) * (float)dold[e];
            }
            unsigned pk = packh2(dn[0], dn[1]);
            ATOMIC_ST64(qd + r * 100 + (n0 >> 1), ((u64)(unsigned)(t + 1) << 32) | pk);
            actG[r * 212 + 100 + (n0 >> 1)] = pk;
            *(float2*)(out + ((size_t)(rb + r) * 64 + t) * 380 + 180 + n0) = make_float2(dn[0], dn[1]);
        }

        // ---- gather remote deter quarters: per-word tagged polls (single RT) ----
        {
            unsigned want = (unsigned)(t + 1);
            int i0 = tid, i1 = tid + 512, i2 = tid + 1024;
            int r0 = i0 / 75, p0 = (25 * (wg + 1) + i0 % 75) % 100;
            int r1 = i1 / 75, p1 = (25 * (wg + 1) + i1 % 75) % 100;
            int r2 = 0, p2 = 0;
            bool h2ok = i2 < 1200;
            if (h2ok) { r2 = i2 / 75; p2 = (25 * (wg + 1) + i2 % 75) % 100; }
            u64 v0 = ATOMIC_LD64(qd + r0 * 100 + p0);
            u64 v1 = ATOMIC_LD64(qd + r1 * 100 + p1);
            u64 v2 = h2ok ? ATOMIC_LD64(qd + r2 * 100 + p2) : 0ull;
            actG[r0 * 212 + 100 + p0] = poll64(qd + r0 * 100 + p0, want, v0);
            actG[r1 * 212 + 100 + p1] = poll64(qd + r1 * 100 + p1, want, v1);
            if (h2ok) actG[r2 * 212 + 100 + p2] = poll64(qd + r2 * 100 + p2, want, v2);
        }
        BAR_LDS();

        // ---- P3 (wg0/wg2): h/ho = elu(deter_new @ W [+ep] + b) -> actX ----
        if (statside) {
            f32x4 acc = {}, acc2 = {};
#pragma unroll
            for (int ks = 0; ks < 7; ++ks) {
                half8 a = *(const half8*)(actG + m * 212 + 100 + ks * 16 + q * 4);
                acc = MFMA16(a, bp3a[ks], acc);
                if (w < 5) acc2 = MFMA16(a, pf3[ks], acc2);
            }
            f32x4 accN;
#pragma unroll
            for (int i = 0; i < 4; ++i) accN[i] = __shfl_xor(acc[i], 1);
            if (!(m & 1)) {
                int bb0 = post ? 1000 : 800;
#pragma unroll
                for (int i = 0; i < 4; ++i) {
                    float e0 = post ? (float)epA[i][0] : 0.0f;
                    float e1 = post ? (float)epA[i][1] : 0.0f;
                    actX[(q * 4 + i) * 116 + (colA >> 1)] =
                        packh2(elu_(acc[i] + bias[bb0 + colA] + e0),
                               elu_(accN[i] + bias[bb0 + colA + 1] + e1));
                }
            }
            if (w < 5) {
                f32x4 acc2N;
#pragma unroll
                for (int i = 0; i < 4; ++i) acc2N[i] = __shfl_xor(acc2[i], 1);
                if (!(m & 1) && colB < 200) {
                    int bb0 = post ? 1000 : 800;
#pragma unroll
                    for (int i = 0; i < 4; ++i) {
                        float e0 = post ? (float)epB[i][0] : 0.0f;
                        float e1 = post ? (float)epB[i][1] : 0.0f;
                        actX[(q * 4 + i) * 116 + (colB >> 1)] =
                            packh2(elu_(acc2[i] + bias[bb0 + colB] + e0),
                                   elu_(acc2N[i] + bias[bb0 + colB + 1] + e1));
                    }
                }
            }
        }
        BAR_LDS();

        // ---- P4 (wg0/wg2, waves 4-7): stats preacts ----
        if (statside && w >= 4) {
            f32x4 acc = {};
#pragma unroll
            for (int ks = 0; ks < 7; ++ks) {
                half8 a = *(const half8*)(actX + m * 116 + ks * 16 + q * 4);
                acc = MFMA16(a, bp4[ks], acc);
            }
#pragma unroll
            for (int i = 0; i < 4; ++i)
                statspre[(q * 4 + i) * 65 + (w - 4) * 16 + m] = acc[i];
        }
        BAR_LDS();

        // ---- P5 (wg0/wg2): mean/std/stoch; wg2 publishes tagged stoch immediately ----
        if (statside && tid < 240) {
            int r = tid / 15, cp = tid % 15;
            int bb0 = post ? 1260 : 1200;
            float m0 = statspre[r * 65 + 2 * cp]     + bias[bb0 + 2 * cp];
            float m1 = statspre[r * 65 + 2 * cp + 1] + bias[bb0 + 2 * cp + 1];
            float s0 = sp_(statspre[r * 65 + 30 + 2 * cp]     + bias[bb0 + 30 + 2 * cp]) + 0.1f;
            float s1 = sp_(statspre[r * 65 + 30 + 2 * cp + 1] + bias[bb0 + 30 + 2 * cp + 1]) + 0.1f;
            float st0 = m0 + s0 * nz.x, st1 = m1 + s1 * nz.y;
            if (post) {
                unsigned pk = packh2(st0, st1);
                ATOMIC_ST64(stochb + (size_t)((t & 1) * 32 + g) * 256 + r * 16 + cp,
                            ((u64)(unsigned)(t + 1) << 32) | pk);
                actI[r * 36 + cp] = pk;
            }
            size_t ob = ((size_t)(rb + r) * 64 + t) * 380;
            int o0 = post ? 0 : 90;
            *(float2*)(out + ob + o0 + 2 * cp)      = make_float2(st0, st1);
            *(float2*)(out + ob + o0 + 30 + 2 * cp) = make_float2(m0, m1);
            *(float2*)(out + ob + o0 + 60 + 2 * cp) = make_float2(s0, s1);
        }
        // next iteration's top BAR_LDS orders P5's actI writes before P1(t+1) reads
    }
}

extern "C" void kernel_launch(void* const* d_in, const int* in_sizes, int n_in,
                              void* d_out, int out_size, void* d_ws, size_t ws_size,
                              hipStream_t stream) {
    const float* embed   = (const float*)d_in[0];
    const float* action  = (const float*)d_in[1];
    const float* npr     = (const float*)d_in[2];
    const float* npo     = (const float*)d_in[3];
    const float* inpW    = (const float*)d_in[4];
    const float* inpb    = (const float*)d_in[5];
    const float* gruW    = (const float*)d_in[6];
    const float* grub    = (const float*)d_in[7];
    const float* imgW    = (const float*)d_in[8];
    const float* imgb    = (const float*)d_in[9];
    const float* imsW    = (const float*)d_in[10];
    const float* imsb    = (const float*)d_in[11];
    const float* obsoutW = (const float*)d_in[12];
    const float* obsoutb = (const float*)d_in[13];
    const float* obsW    = (const float*)d_in[14];
    const float* obsb    = (const float*)d_in[15];

    char* ws = (char*)d_ws;
    _Float16* ep     = (_Float16*)ws;                              // 13,107,200 B
    _Float16* frags  = (_Float16*)(ws + EP_HALVES * 2);            // 1,202,176 B
    char* p          = ws + EP_HALVES * 2 + (size_t)1174 * 1024;
    u64* qdetb       = (u64*)p;                                    // 2*32*1600*8 = 819,200 B
    p += (size_t)2 * 32 * 1600 * 8;
    u64* stochb      = (u64*)p;                                    // 2*32*256*8 = 131,072 B
    // total 15,259,648 B (< previous 15,374,336)

    prep_frags<<<1174, 64, 0, stream>>>(inpW, gruW, imgW, obsoutW, imsW, obsW, frags);
    ep_gemm<<<2048, 256, 0, stream>>>(embed, frags + (size_t)758 * 512, ep, qdetb);
    rssm_scan<<<128, 512, 0, stream>>>(action, npr, npo, inpb, grub, imgb, obsoutb,
                                       imsb, obsb, frags, ep, qdetb, stochb,
                                       (float*)d_out);
}

// Round 3
// 844.336 us; speedup vs baseline: 1.1957x; 1.1957x over previous
//
#include <hip/hip_runtime.h>

typedef _Float16 h2   __attribute__((ext_vector_type(2)));
typedef _Float16 h4   __attribute__((ext_vector_type(4)));
typedef _Float16 half8 __attribute__((ext_vector_type(8)));
typedef float f32x4   __attribute__((ext_vector_type(4)));

#define MFMA16(a,b,c) __builtin_amdgcn_mfma_f32_16x16x32_f16((a),(b),(c),0,0,0)
#define ATOMIC_ST(p,v) __hip_atomic_store((p),(v),__ATOMIC_RELAXED,__HIP_MEMORY_SCOPE_AGENT)
#define ATOMIC_LD(p)   __hip_atomic_load((p),__ATOMIC_RELAXED,__HIP_MEMORY_SCOPE_AGENT)
// Light barrier: rendezvous + LDS drain only. Global loads/stores stay in flight.
#define BAR_LDS() do { asm volatile("s_waitcnt lgkmcnt(0)" ::: "memory"); \
                       __builtin_amdgcn_s_barrier();                      \
                       asm volatile("" ::: "memory"); } while (0)

// B=512, T=64, STOCH=30, DETER=200, HIDDEN=200, A=12, EMBED=1024
// out row = [stoch_po(30), mean_po(30), std_po(30), stoch_pr(30), mean_pr(30), std_pr(30), deter(200)] = 380

// Fragment regions (1KB blocks = 64 lanes x 8 halves), B-frag order [nt][ks][lane][8]
// INP: NT=13 KS=2 @0(26) | GRU: NT=38 KS=13 @26(494) | IMG: NT=13 KS=7 @520(91)
// OBSD: NT=13 KS=7 @611(91) | IMS: NT=4 KS=7 @702(28) | OBS: NT=4 KS=7 @730(28)
// W2: NT=13 KS=32 @758(416) -> 1174 blocks
#define EP_HALVES ((size_t)32768*200)

__global__ void prep_frags(const float* __restrict__ inpW, const float* __restrict__ gruW,
                           const float* __restrict__ imgW, const float* __restrict__ obsoutW,
                           const float* __restrict__ imsW, const float* __restrict__ obsW,
                           _Float16* __restrict__ frags) {
    int gb = blockIdx.x, lane = threadIdx.x;
    const float* src; int KS, K, N, ld, roff = 0, local;
    if (gb < 26)       { src = inpW;    KS = 2;  K = 42;   N = 200; ld = 200; local = gb; }
    else if (gb < 520) { src = gruW;    KS = 13; K = 400;  N = 600; ld = 600; local = gb - 26; }
    else if (gb < 611) { src = imgW;    KS = 7;  K = 200;  N = 200; ld = 200; local = gb - 520; }
    else if (gb < 702) { src = obsoutW; KS = 7;  K = 200;  N = 200; ld = 200; local = gb - 611; }
    else if (gb < 730) { src = imsW;    KS = 7;  K = 200;  N = 60;  ld = 60;  local = gb - 702; }
    else if (gb < 758) { src = obsW;    KS = 7;  K = 200;  N = 60;  ld = 60;  local = gb - 730; }
    else               { src = obsoutW; KS = 32; K = 1024; N = 200; ld = 200; roff = 200; local = gb - 758; }
    int nt = local / KS, ks = local % KS;
    int n  = nt * 16 + (lane & 15);
    int k0 = ks * 32 + (lane >> 4) * 8;
    half8 v;
#pragma unroll
    for (int j = 0; j < 8; ++j) {
        int k = k0 + j;
        float f = (k < K && n < N) ? src[(size_t)(k + roff) * ld + n] : 0.0f;
        v[j] = (_Float16)f;
    }
    *(half8*)(frags + (size_t)gb * 512 + lane * 8) = v;
}

// ep[row][0..199] = embed[row] @ obs_out_W[200:,:]  (f16), row = b*64+t
__global__ __launch_bounds__(256) void ep_gemm(const float* __restrict__ embed,
                                               const _Float16* __restrict__ w2f,
                                               _Float16* __restrict__ ep) {
    __shared__ __align__(16) _Float16 aE[16 * 1048];
    int tid = threadIdx.x;
    int rb = blockIdx.x * 16;
#pragma unroll
    for (int i = 0; i < 16; ++i) {
        float4 e = *((const float4*)(embed + (size_t)(rb + i) * 1024) + tid);
        h4 hv; hv[0] = (_Float16)e.x; hv[1] = (_Float16)e.y; hv[2] = (_Float16)e.z; hv[3] = (_Float16)e.w;
        *(h4*)(aE + i * 1048 + tid * 4) = hv;
    }
    __syncthreads();
    int w = tid >> 6, lane = tid & 63, m = lane & 15, q = lane >> 4;
    f32x4 acc[4] = {};
    int nts[4]; int ntc = 0;
    for (int nt = w; nt < 13; nt += 4) nts[ntc++] = nt;
    half8 bb[2][4];
#pragma unroll
    for (int j = 0; j < 4; ++j) if (j < ntc)
        bb[0][j] = *(const half8*)(w2f + ((size_t)(nts[j] * 32) * 64 + lane) * 8);
#pragma unroll
    for (int ks = 0; ks < 32; ++ks) {
        int cur = ks & 1, nxt = cur ^ 1;
        if (ks < 31) {
#pragma unroll
            for (int j = 0; j < 4; ++j) if (j < ntc)
                bb[nxt][j] = *(const half8*)(w2f + ((size_t)(nts[j] * 32 + ks + 1) * 64 + lane) * 8);
        }
        half8 a = *(const half8*)(aE + m * 1048 + ks * 32 + q * 8);
#pragma unroll
        for (int j = 0; j < 4; ++j) if (j < ntc)
            acc[j] = MFMA16(a, bb[cur][j], acc[j]);
    }
    for (int j = 0; j < ntc; ++j) {
        int col = nts[j] * 16 + m;
        if (col < 200) {
#pragma unroll
            for (int i = 0; i < 4; ++i)
                ep[(size_t)(rb + q * 4 + i) * 200 + col] = (_Float16)acc[j][i];
        }
    }
}

__device__ __forceinline__ float sigm_(float x) { return 1.0f / (1.0f + __expf(-x)); }
__device__ __forceinline__ float tanh_(float x) { float e = __expf(2.0f * x); return 1.0f - 2.0f / (e + 1.0f); }
__device__ __forceinline__ float elu_(float x)  { return x > 0.0f ? x : __expf(x) - 1.0f; }
__device__ __forceinline__ float sp_(float x)   { return fmaxf(x, 0.0f) + log1pf(__expf(-fabsf(x))); }
__device__ __forceinline__ unsigned packh2(float a, float b) {
    h2 p; p[0] = (_Float16)a; p[1] = (_Float16)b;
    return __builtin_bit_cast(unsigned, p);
}

// 5-WG design: group g = 16 rows, blockIdx = wg*32+g, wg=0..4.
//   wg0..3 (main): GRU quarter n in [50wg,50wg+50) + FULL posterior redundantly.
//     All four compute bit-identical stoch_po locally (deterministic MFMA, identical
//     inputs: exchanged deter bits, same ep/OBSD/OBS/npo) -> NO stoch exchange, no
//     wait on wg2's tail. Only wg2 writes posterior HBM outs.
//   wg4 (prior): trails off the critical path. Polls the 4 deter flags, gathers full
//     deter, computes IMG/IMS prior outs. Posts monotonic progress word gf[508]
//     AFTER consuming each gather; wg0-3 require progress >= t-1 before overwriting
//     the parity buffer at gates(t). The check uses a value PREFETCHED mid-previous
//     step (always satisfied in steady state -> no added latency; spin = rare path).
//   Deter exchange: R1's proven protocol (full __syncthreads drain -> flag post ->
//   tid<3 spin -> bulk loads). Tagged-word variant (R2) measured WORSE: per-word
//   divergent polls cost >=2 RTs each + doubled traffic (FETCH 28->45.5 MB).
//   All other barriers BAR_LDS (lgkm-only): prefetches/out-stores stay in flight.
__global__ __launch_bounds__(512) __attribute__((amdgpu_waves_per_eu(2, 2))) void rssm_scan(
    const float* __restrict__ action, const float* __restrict__ npr, const float* __restrict__ npo,
    const float* __restrict__ inp_b, const float* __restrict__ gru_b,
    const float* __restrict__ img_b, const float* __restrict__ obsout_b,
    const float* __restrict__ ims_b, const float* __restrict__ obs_b,
    const _Float16* __restrict__ frags, const _Float16* __restrict__ ep,
    unsigned* __restrict__ qdet, unsigned* __restrict__ flags,
    float* __restrict__ out) {

    __shared__ __align__(16) unsigned actI[16 * 36];    // [stoch(15p) action(6p) zeropad]
    __shared__ __align__(16) unsigned actG[16 * 212];   // [x(100p) deter(100p) zeropad]
    __shared__ __align__(16) unsigned actX[16 * 116];   // h / ho
    __shared__ __align__(16) _Float16 parts[16 * 208];  // local 12 GRU tiles (f16)
    __shared__ float statspre[16 * 65];
    __shared__ float bias[1320];  // inp200 | gru600 | img200 | obsout200 | ims60 | obs60

    const _Float16* Finp  = frags;
    const _Float16* Fgru  = frags + (size_t)26  * 512;
    const _Float16* Fimg  = frags + (size_t)520 * 512;
    const _Float16* Fobsd = frags + (size_t)611 * 512;
    const _Float16* Fims  = frags + (size_t)702 * 512;
    const _Float16* Fobs  = frags + (size_t)730 * 512;

    const int tid = threadIdx.x, w = tid >> 6, lane = tid & 63, m = lane & 15, q = lane >> 4;
    const int g = blockIdx.x & 31, wg = blockIdx.x >> 5;   // wg 0..4
    const int rb = g * 16;
    const int colA = w * 16 + m;
    const int colB = (8 + w) * 16 + m;
    unsigned* gf = flags + g * 512;   // [t(64)][slot(8)]: 0..3 deter per wg; [508]=wg4 progress

    for (int i = tid; i < 1320; i += 512) {
        float v;
        if (i < 200) v = inp_b[i];
        else if (i < 800)  v = gru_b[i - 200];
        else if (i < 1000) v = img_b[i - 800];
        else if (i < 1200) v = obsout_b[i - 1000];
        else if (i < 1260) v = ims_b[i - 1200];
        else               v = obs_b[i - 1260];
        bias[i] = v;
    }
    for (int i = tid; i < 16 * 36;  i += 512) actI[i] = 0u;
    for (int i = tid; i < 16 * 212; i += 512) actG[i] = 0u;
    for (int i = tid; i < 16 * 116; i += 512) actX[i] = 0u;

    if (wg < 4) {
        // ================= main path: GRU quarter + full posterior =================
        half8 bgru0[13];  // w<4 -> gate0 tile 3wg+w ; w>=4 -> gate1 tile 12+3wg+(w-4)
        {
            int tA = (w < 4) ? (3 * wg + w) : (12 + 3 * wg + (w - 4));
#pragma unroll
            for (int ks = 0; ks < 13; ++ks)
                bgru0[ks] = *(const half8*)(Fgru + ((size_t)(tA * 13 + ks) * 64 + lane) * 8);
        }
        half8 bgru1[13];  // w<4: gate2 tile 25+3wg+w
        if (w < 4) {
            int tB = 25 + 3 * wg + w;
#pragma unroll
            for (int ks = 0; ks < 13; ++ks)
                bgru1[ks] = *(const half8*)(Fgru + ((size_t)(tB * 13 + ks) * 64 + lane) * 8);
        }
        half8 bi0[2], bi1[2];  // INP weights persistent
#pragma unroll
        for (int ks = 0; ks < 2; ++ks)
            bi0[ks] = *(const half8*)(Finp + ((size_t)(w * 2 + ks) * 64 + lane) * 8);
        if (w < 5) {
#pragma unroll
            for (int ks = 0; ks < 2; ++ks)
                bi1[ks] = *(const half8*)(Finp + ((size_t)((8 + w) * 2 + ks) * 64 + lane) * 8);
        }
        half8 bp3a[7];    // OBSD tile w
#pragma unroll
        for (int ks = 0; ks < 7; ++ks)
            bp3a[ks] = *(const half8*)(Fobsd + ((size_t)(w * 7 + ks) * 64 + lane) * 8);
        half8 bp4[7];     // w in 4..7: OBS tile w-4
        if (w >= 4) {
#pragma unroll
            for (int ks = 0; ks < 7; ++ks)
                bp4[ks] = *(const half8*)(Fobs + ((size_t)((w - 4) * 7 + ks) * 64 + lane) * 8);
        }
        __syncthreads();

        unsigned wg4pf = 0u;   // prefetched wg4 progress (tid 3 owns it)
        for (int t = 0; t < 64; ++t) {
            // ---- prefetches: ep, action, noise (fire-and-forget) ----
            h2 epA[4], epB[4];
            if (!(m & 1)) {
#pragma unroll
                for (int i = 0; i < 4; ++i)
                    epA[i] = *(const h2*)(ep + ((size_t)(rb + q * 4 + i) * 64 + t) * 200 + colA);
                if (w < 5 && colB < 200) {
#pragma unroll
                    for (int i = 0; i < 4; ++i)
                        epB[i] = *(const h2*)(ep + ((size_t)(rb + q * 4 + i) * 64 + t) * 200 + colB);
                }
            }
            float2 a2 = make_float2(0.0f, 0.0f);
            if (tid < 96) {
                int r = tid / 6, cp = tid % 6;
                a2 = *(const float2*)(action + ((size_t)(rb + r) * 64 + t) * 12 + 2 * cp);
            }
            float2 nz = make_float2(0.0f, 0.0f);
            if (tid < 240) {
                int r = tid / 15, cp = tid % 15;
                nz = *(const float2*)(npo + ((size_t)(rb + r) * 64 + t) * 30 + 2 * cp);
            }
            // ---- wg4 progress check (rarely blocking; value prefetched mid-prev-step) ----
            if (t >= 2 && tid == 3 && wg4pf < (unsigned)(t - 1)) {
                int it = 0;
                unsigned v = ATOMIC_LD(gf + 508);
                while (v < (unsigned)(t - 1)) {
                    __builtin_amdgcn_s_sleep(1);
                    v = ATOMIC_LD(gf + 508);
                    if (++it > (1 << 20)) break;
                }
                wg4pf = v;
            }
            if (tid < 96) {
                int r = tid / 6, cp = tid % 6;
                actI[r * 36 + 15 + cp] = packh2(a2.x, a2.y);
            }
            BAR_LDS();   // also orders P5(t-1) actI writes before P1 reads

            // ---- P1: x = elu(cat(stoch,action)@inp_W + b) -> actG[0..99] ----
            {
                f32x4 acc = {}, acc2 = {};
#pragma unroll
                for (int ks = 0; ks < 2; ++ks) {
                    half8 a = *(const half8*)(actI + m * 36 + ks * 16 + q * 4);
                    acc = MFMA16(a, bi0[ks], acc);
                    if (w < 5) acc2 = MFMA16(a, bi1[ks], acc2);
                }
                f32x4 accN;
#pragma unroll
                for (int i = 0; i < 4; ++i) accN[i] = __shfl_xor(acc[i], 1);
                if (!(m & 1)) {
                    int col = w * 16 + m;
#pragma unroll
                    for (int i = 0; i < 4; ++i)
                        actG[(q * 4 + i) * 212 + (col >> 1)] =
                            packh2(elu_(acc[i] + bias[col]), elu_(accN[i] + bias[col + 1]));
                }
                if (w < 5) {
                    f32x4 acc2N;
#pragma unroll
                    for (int i = 0; i < 4; ++i) acc2N[i] = __shfl_xor(acc2[i], 1);
                    if (!(m & 1)) {
                        int col = (8 + w) * 16 + m;
                        if (col < 200) {
#pragma unroll
                            for (int i = 0; i < 4; ++i)
                                actG[(q * 4 + i) * 212 + (col >> 1)] =
                                    packh2(elu_(acc2[i] + bias[col]), elu_(acc2N[i] + bias[col + 1]));
                        }
                    }
                }
            }
            BAR_LDS();

            // ---- P2: local 12 GRU tiles -> parts ----
            {
                f32x4 a0 = {}, a1 = {};
#pragma unroll
                for (int ks = 0; ks < 13; ++ks) {
                    half8 a = *(const half8*)(actG + m * 212 + ks * 16 + q * 4);
                    a0 = MFMA16(a, bgru0[ks], a0);
                    if (w < 4) a1 = MFMA16(a, bgru1[ks], a1);
                }
#pragma unroll
                for (int i = 0; i < 4; ++i)
                    parts[(q * 4 + i) * 208 + w * 16 + m] = (_Float16)a0[i];
                if (w < 4) {
#pragma unroll
                    for (int i = 0; i < 4; ++i)
                        parts[(q * 4 + i) * 208 + (8 + w) * 16 + m] = (_Float16)a1[i];
                }
            }
            // stream OBSD tile 8+w (stays in flight across light barriers)
            half8 pf3[7];
            if (w < 5) {
#pragma unroll
                for (int ks = 0; ks < 7; ++ks)
                    pf3[ks] = *(const half8*)(Fobsd + ((size_t)((8 + w) * 7 + ks) * 64 + lane) * 8);
            }
            BAR_LDS();

            // ---- gates: own n-quarter -> deter_new ----
            unsigned* qd = qdet + (size_t)((t & 1) * 32 + g) * 1600;
            float gdn0 = 0.0f, gdn1 = 0.0f; int gr = 0, gn0 = 0;
            if (tid < 400) {
                int r = tid / 25, p = tid % 25;
                int n0 = 50 * wg + 2 * p;
                float pg[3][2];
#pragma unroll
                for (int j = 0; j < 3; ++j) {
                    int cg = n0 + 200 * j;
                    int bj = (j == 0) ? 3 * wg : (j == 1) ? 12 + 3 * wg : 25 + 3 * wg;
                    int lt = 4 * j + (cg >> 4) - bj;
                    h2 v = *(const h2*)(parts + r * 208 + lt * 16 + (cg & 15));
                    pg[j][0] = (float)v[0] + bias[200 + cg];
                    pg[j][1] = (float)v[1] + bias[200 + cg + 1];
                }
                h2 dold = *(const h2*)&actG[r * 212 + 100 + (n0 >> 1)];
                float dn[2];
#pragma unroll
                for (int e = 0; e < 2; ++e) {
                    float reset = sigm_(pg[0][e]);
                    float cand  = tanh_(reset * pg[1][e]);
                    float upd   = sigm_(pg[2][e] - 1.0f);
                    dn[e] = upd * cand + (1.0f - upd) * (float)dold[e];
                }
                unsigned pk = packh2(dn[0], dn[1]);
                actG[r * 212 + 100 + (n0 >> 1)] = pk;
                ATOMIC_ST(qd + r * 100 + (n0 >> 1), pk);
                gdn0 = dn[0]; gdn1 = dn[1]; gr = r; gn0 = n0;
            }
            __syncthreads();              // FULL drain: qdet stores complete before flag post

            // ---- deter exchange (R1 protocol) ----
            __atomic_signal_fence(__ATOMIC_RELEASE);
            if (tid == 0) ATOMIC_ST(gf + t * 8 + wg, (unsigned)(t + 1));
            if (tid < 400)
                *(float2*)(out + ((size_t)(rb + gr) * 64 + t) * 380 + 180 + gn0) = make_float2(gdn0, gdn1);
            if (tid < 3) {
                unsigned* f = gf + t * 8 + ((wg + 1 + tid) & 3);
                int it = 0;
                while (ATOMIC_LD(f) != (unsigned)(t + 1)) {
                    __builtin_amdgcn_s_sleep(1);
                    if (++it > (1 << 20)) break;
                }
            }
            BAR_LDS();
            __atomic_signal_fence(__ATOMIC_ACQUIRE);
            for (int i = tid; i < 1200; i += 512) {
                int r = i / 75, idx = i % 75;
                int pp = (25 * (wg + 1) + idx) % 100;
                actG[r * 212 + 100 + pp] = ATOMIC_LD(qd + r * 100 + pp);
            }
            if (tid == 3) wg4pf = ATOMIC_LD(gf + 508);   // prefetch for next step's check
            BAR_LDS();

            // ---- P3: ho = elu(deter_new @ OBSD + ep + b) -> actX ----
            {
                f32x4 acc = {}, acc2 = {};
#pragma unroll
                for (int ks = 0; ks < 7; ++ks) {
                    half8 a = *(const half8*)(actG + m * 212 + 100 + ks * 16 + q * 4);
                    acc = MFMA16(a, bp3a[ks], acc);
                    if (w < 5) acc2 = MFMA16(a, pf3[ks], acc2);
                }
                f32x4 accN;
#pragma unroll
                for (int i = 0; i < 4; ++i) accN[i] = __shfl_xor(acc[i], 1);
                if (!(m & 1)) {
#pragma unroll
                    for (int i = 0; i < 4; ++i)
                        actX[(q * 4 + i) * 116 + (colA >> 1)] =
                            packh2(elu_(acc[i] + bias[1000 + colA] + (float)epA[i][0]),
                                   elu_(accN[i] + bias[1000 + colA + 1] + (float)epA[i][1]));
                }
                if (w < 5) {
                    f32x4 acc2N;
#pragma unroll
                    for (int i = 0; i < 4; ++i) acc2N[i] = __shfl_xor(acc2[i], 1);
                    if (!(m & 1) && colB < 200) {
#pragma unroll
                        for (int i = 0; i < 4; ++i)
                            actX[(q * 4 + i) * 116 + (colB >> 1)] =
                                packh2(elu_(acc2[i] + bias[1000 + colB] + (float)epB[i][0]),
                                       elu_(acc2N[i] + bias[1000 + colB + 1] + (float)epB[i][1]));
                    }
                }
            }
            BAR_LDS();

            // ---- P4 (waves 4-7): stats preacts (OBS) ----
            if (w >= 4) {
                f32x4 acc = {};
#pragma unroll
                for (int ks = 0; ks < 7; ++ks) {
                    half8 a = *(const half8*)(actX + m * 116 + ks * 16 + q * 4);
                    acc = MFMA16(a, bp4[ks], acc);
                }
#pragma unroll
                for (int i = 0; i < 4; ++i)
                    statspre[(q * 4 + i) * 65 + (w - 4) * 16 + m] = acc[i];
            }
            BAR_LDS();

            // ---- P5: mean/std/stoch_po; ALL wg0-3 keep stoch locally; wg2 writes HBM ----
            if (tid < 240) {
                int r = tid / 15, cp = tid % 15;
                float m0 = statspre[r * 65 + 2 * cp]     + bias[1260 + 2 * cp];
                float m1 = statspre[r * 65 + 2 * cp + 1] + bias[1260 + 2 * cp + 1];
                float s0 = sp_(statspre[r * 65 + 30 + 2 * cp]     + bias[1260 + 30 + 2 * cp]) + 0.1f;
                float s1 = sp_(statspre[r * 65 + 30 + 2 * cp + 1] + bias[1260 + 30 + 2 * cp + 1]) + 0.1f;
                float st0 = m0 + s0 * nz.x, st1 = m1 + s1 * nz.y;
                actI[r * 36 + cp] = packh2(st0, st1);
                if (wg == 2) {
                    size_t ob = ((size_t)(rb + r) * 64 + t) * 380;
                    *(float2*)(out + ob + 2 * cp)      = make_float2(st0, st1);
                    *(float2*)(out + ob + 30 + 2 * cp) = make_float2(m0, m1);
                    *(float2*)(out + ob + 60 + 2 * cp) = make_float2(s0, s1);
                }
            }
            // next step-top BAR_LDS orders actI writes before P1(t+1) reads
        }
    } else {
        // ================= wg4: prior path (off critical path) =================
        half8 bp3a[7];    // IMG tile w
#pragma unroll
        for (int ks = 0; ks < 7; ++ks)
            bp3a[ks] = *(const half8*)(Fimg + ((size_t)(w * 7 + ks) * 64 + lane) * 8);
        half8 bp3b[7];    // IMG tile 8+w (persistent; wg4 has register headroom)
        if (w < 5) {
#pragma unroll
            for (int ks = 0; ks < 7; ++ks)
                bp3b[ks] = *(const half8*)(Fimg + ((size_t)((8 + w) * 7 + ks) * 64 + lane) * 8);
        }
        half8 bp4[7];     // IMS tile w-4
        if (w >= 4) {
#pragma unroll
            for (int ks = 0; ks < 7; ++ks)
                bp4[ks] = *(const half8*)(Fims + ((size_t)((w - 4) * 7 + ks) * 64 + lane) * 8);
        }
        __syncthreads();

        for (int t = 0; t < 64; ++t) {
            float2 nz = make_float2(0.0f, 0.0f);
            if (tid < 240) {
                int r = tid / 15, cp = tid % 15;
                nz = *(const float2*)(npr + ((size_t)(rb + r) * 64 + t) * 30 + 2 * cp);
            }
            if (tid < 4) {
                unsigned* f = gf + t * 8 + tid;
                int it = 0;
                while (ATOMIC_LD(f) != (unsigned)(t + 1)) {
                    __builtin_amdgcn_s_sleep(1);
                    if (++it > (1 << 20)) break;
                }
            }
            BAR_LDS();
            __atomic_signal_fence(__ATOMIC_ACQUIRE);
            const unsigned* qd = qdet + (size_t)((t & 1) * 32 + g) * 1600;
            for (int i = tid; i < 1600; i += 512)
                actG[(i / 100) * 212 + 100 + (i % 100)] = ATOMIC_LD(qd + i);
            BAR_LDS();   // gather consumed (loads completed via data dep on ds_writes)
            __atomic_signal_fence(__ATOMIC_RELEASE);
            if (tid == 0) ATOMIC_ST(gf + 508, (unsigned)(t + 1));   // progress post

            // ---- P3 prior: h = elu(deter_new @ IMG + b) -> actX ----
            {
                f32x4 acc = {}, acc2 = {};
#pragma unroll
                for (int ks = 0; ks < 7; ++ks) {
                    half8 a = *(const half8*)(actG + m * 212 + 100 + ks * 16 + q * 4);
                    acc = MFMA16(a, bp3a[ks], acc);
                    if (w < 5) acc2 = MFMA16(a, bp3b[ks], acc2);
                }
                f32x4 accN;
#pragma unroll
                for (int i = 0; i < 4; ++i) accN[i] = __shfl_xor(acc[i], 1);
                if (!(m & 1)) {
#pragma unroll
                    for (int i = 0; i < 4; ++i)
                        actX[(q * 4 + i) * 116 + (colA >> 1)] =
                            packh2(elu_(acc[i] + bias[800 + colA]),
                                   elu_(accN[i] + bias[800 + colA + 1]));
                }
                if (w < 5) {
                    f32x4 acc2N;
#pragma unroll
                    for (int i = 0; i < 4; ++i) acc2N[i] = __shfl_xor(acc2[i], 1);
                    if (!(m & 1) && colB < 200) {
#pragma unroll
                        for (int i = 0; i < 4; ++i)
                            actX[(q * 4 + i) * 116 + (colB >> 1)] =
                                packh2(elu_(acc2[i] + bias[800 + colB]),
                                       elu_(acc2N[i] + bias[800 + colB + 1]));
                    }
                }
            }
            BAR_LDS();

            // ---- P4 (waves 4-7): stats preacts (IMS) ----
            if (w >= 4) {
                f32x4 acc = {};
#pragma unroll
                for (int ks = 0; ks < 7; ++ks) {
                    half8 a = *(const half8*)(actX + m * 116 + ks * 16 + q * 4);
                    acc = MFMA16(a, bp4[ks], acc);
                }
#pragma unroll
                for (int i = 0; i < 4; ++i)
                    statspre[(q * 4 + i) * 65 + (w - 4) * 16 + m] = acc[i];
            }
            BAR_LDS();

            // ---- P5: prior outs ----
            if (tid < 240) {
                int r = tid / 15, cp = tid % 15;
                float m0 = statspre[r * 65 + 2 * cp]     + bias[1200 + 2 * cp];
                float m1 = statspre[r * 65 + 2 * cp + 1] + bias[1200 + 2 * cp + 1];
                float s0 = sp_(statspre[r * 65 + 30 + 2 * cp]     + bias[1200 + 30 + 2 * cp]) + 0.1f;
                float s1 = sp_(statspre[r * 65 + 30 + 2 * cp + 1] + bias[1200 + 30 + 2 * cp + 1]) + 0.1f;
                float st0 = m0 + s0 * nz.x, st1 = m1 + s1 * nz.y;
                size_t ob = ((size_t)(rb + r) * 64 + t) * 380;
                *(float2*)(out + ob + 90 + 2 * cp)  = make_float2(st0, st1);
                *(float2*)(out + ob + 120 + 2 * cp) = make_float2(m0, m1);
                *(float2*)(out + ob + 150 + 2 * cp) = make_float2(s0, s1);
            }
            // statspre(t+1) writes are fenced from P5 reads by the spin/gather barriers
        }
    }
}

extern "C" void kernel_launch(void* const* d_in, const int* in_sizes, int n_in,
                              void* d_out, int out_size, void* d_ws, size_t ws_size,
                              hipStream_t stream) {
    const float* embed   = (const float*)d_in[0];
    const float* action  = (const float*)d_in[1];
    const float* npr     = (const float*)d_in[2];
    const float* npo     = (const float*)d_in[3];
    const float* inpW    = (const float*)d_in[4];
    const float* inpb    = (const float*)d_in[5];
    const float* gruW    = (const float*)d_in[6];
    const float* grub    = (const float*)d_in[7];
    const float* imgW    = (const float*)d_in[8];
    const float* imgb    = (const float*)d_in[9];
    const float* imsW    = (const float*)d_in[10];
    const float* imsb    = (const float*)d_in[11];
    const float* obsoutW = (const float*)d_in[12];
    const float* obsoutb = (const float*)d_in[13];
    const float* obsW    = (const float*)d_in[14];
    const float* obsb    = (const float*)d_in[15];

    char* ws = (char*)d_ws;
    _Float16* ep     = (_Float16*)ws;                              // 13,107,200 B
    _Float16* frags  = (_Float16*)(ws + EP_HALVES * 2);            // 1,202,176 B
    char* p          = ws + EP_HALVES * 2 + (size_t)1174 * 1024;
    unsigned* qdetb  = (unsigned*)p;                               // 2*32*1600*4 = 409,600 B
    p += (size_t)2 * 32 * 1600 * 4;
    unsigned* flagsb = (unsigned*)p;                               // 32*512*4 = 65,536 B
    // total 14,784,512 B

    prep_frags<<<1174, 64, 0, stream>>>(inpW, gruW, imgW, obsoutW, imsW, obsW, frags);
    ep_gemm<<<2048, 256, 0, stream>>>(embed, frags + (size_t)758 * 512, ep);
    rssm_scan<<<160, 512, 0, stream>>>(action, npr, npo, inpb, grub, imgb, obsoutb,
                                       imsb, obsb, frags, ep, qdetb, flagsb,
                                       (float*)d_out);
}